// Round 1
// baseline (1751.736 us; speedup 1.0000x reference)
//
#include <hip/hip_runtime.h>
#include <math.h>

#define B    64
#define T    4096
#define DENC 512
#define DDEC 512
#define DATT 256

// ---------------------------------------------------------------------------
// K1: qq[b,a] = dot(Wq_w[a,:], h_dec[b,:]) + Wq_b[a] + Wk_b[a]
// (Wk_b folded in here so K2's epilogue only needs qq + raw GEMM result)
// ---------------------------------------------------------------------------
__global__ __launch_bounds__(256) void k_qproj(const float* __restrict__ h_dec,
                                               const float* __restrict__ Wq_w,
                                               const float* __restrict__ Wq_b,
                                               const float* __restrict__ Wk_b,
                                               float* __restrict__ qq) {
    __shared__ float sh[DDEC];
    const int b = blockIdx.x;
    const int tid = threadIdx.x;
    // stage h_dec row (512 floats) into LDS: 256 threads x float2
    ((float2*)sh)[tid] = ((const float2*)(h_dec + (size_t)b * DDEC))[tid];
    __syncthreads();
    const int a = tid;  // 256 outputs per block
    const float4* wr  = (const float4*)(Wq_w + (size_t)a * DDEC);
    const float4* shv = (const float4*)sh;
    float acc = 0.f;
#pragma unroll 4
    for (int i = 0; i < DDEC / 4; ++i) {
        float4 wv = wr[i];
        float4 hv = shv[i];
        acc += wv.x * hv.x + wv.y * hv.y + wv.z * hv.z + wv.w * hv.w;
    }
    qq[b * DATT + a] = acc + Wq_b[a] + Wk_b[a];
}

// ---------------------------------------------------------------------------
// K2: fused k-projection + additive score.
//   Tiled f32 GEMM: per block, tile = BM(=64) t-rows x DATT(=256) a-cols, K=512
//   epilogue: s[t] = sum_a v[a]*tanh(qq[b,a] + k[t,a]); mask; write scores.
//   Thread microtile: 8 t x 8 a (a strided by 32 -> conflict-free LDS reads).
// ---------------------------------------------------------------------------
#define BM   64
#define BK   32
#define PADA 4
#define PADB 4

__global__ __launch_bounds__(256, 2) void k_score(const float* __restrict__ h_enc,
                                                  const float* __restrict__ Wk_w,
                                                  const float* __restrict__ qq,
                                                  const float* __restrict__ v_w,
                                                  const int* __restrict__ mask,
                                                  float* __restrict__ scores) {
    __shared__ float As[BK][BM + PADA];    // h_enc tile, transposed: As[k][t]
    __shared__ float Bs[BK][DATT + PADB];  // Wk tile, transposed:   Bs[k][a]

    const int tc  = blockIdx.x;   // t-chunk
    const int b   = blockIdx.y;
    const int tid = threadIdx.x;
    const int t0  = tc * BM;
    const int trow = tid >> 5;    // 0..7  -> t microtile = trow*8 .. trow*8+7
    const int tcol = tid & 31;    // 0..31 -> a microtile = tcol + 32*j

    float acc[8][8];
#pragma unroll
    for (int i = 0; i < 8; ++i)
#pragma unroll
        for (int j = 0; j < 8; ++j) acc[i][j] = 0.f;

    const float* Abase = h_enc + ((size_t)b * T + t0) * DENC;

    for (int k0 = 0; k0 < DENC; k0 += BK) {
        // A tile: 64 rows x 32 cols = 512 float4 -> 2 per thread
#pragma unroll
        for (int r = 0; r < 2; ++r) {
            int idx = r * 256 + tid;
            int row = idx >> 3, c4 = idx & 7;
            float4 v = *(const float4*)(Abase + (size_t)row * DENC + k0 + c4 * 4);
            As[c4 * 4 + 0][row] = v.x;
            As[c4 * 4 + 1][row] = v.y;
            As[c4 * 4 + 2][row] = v.z;
            As[c4 * 4 + 3][row] = v.w;
        }
        // B tile: 256 rows x 32 cols = 2048 float4 -> 8 per thread
#pragma unroll
        for (int r = 0; r < 8; ++r) {
            int idx = r * 256 + tid;
            int row = idx >> 3, c4 = idx & 7;
            float4 v = *(const float4*)(Wk_w + (size_t)row * DENC + k0 + c4 * 4);
            Bs[c4 * 4 + 0][row] = v.x;
            Bs[c4 * 4 + 1][row] = v.y;
            Bs[c4 * 4 + 2][row] = v.z;
            Bs[c4 * 4 + 3][row] = v.w;
        }
        __syncthreads();

#pragma unroll
        for (int kk = 0; kk < BK; ++kk) {
            float af[8], bf[8];
            // broadcast read (all lanes in half-wave hit same addr): free
            const float4* ap = (const float4*)&As[kk][trow * 8];
            float4 a0 = ap[0], a1 = ap[1];
            af[0] = a0.x; af[1] = a0.y; af[2] = a0.z; af[3] = a0.w;
            af[4] = a1.x; af[5] = a1.y; af[6] = a1.z; af[7] = a1.w;
#pragma unroll
            for (int j = 0; j < 8; ++j) bf[j] = Bs[kk][tcol + 32 * j];
#pragma unroll
            for (int i = 0; i < 8; ++i)
#pragma unroll
                for (int j = 0; j < 8; ++j) acc[i][j] += af[i] * bf[j];
        }
        __syncthreads();
    }

    // epilogue: s[t] = sum_a v[a] * tanh(qq[a] + k[t,a]); mask; store.
    float qr[8], vr[8];
#pragma unroll
    for (int j = 0; j < 8; ++j) {
        qr[j] = qq[b * DATT + tcol + 32 * j];
        vr[j] = v_w[tcol + 32 * j];
    }
#pragma unroll
    for (int i = 0; i < 8; ++i) {
        float s = 0.f;
#pragma unroll
        for (int j = 0; j < 8; ++j) s += vr[j] * tanhf(qr[j] + acc[i][j]);
        // butterfly sum within each 32-lane half (trow is uniform per half)
#pragma unroll
        for (int off = 1; off < 32; off <<= 1) s += __shfl_xor(s, off, 64);
        if (tcol == 0) {
            int t = t0 + trow * 8 + i;
            bool m = mask[(size_t)b * T + t] != 0;
            scores[(size_t)b * T + t] = m ? s : -1e9f;
        }
    }
}

// ---------------------------------------------------------------------------
// K3: in-place masked softmax over T per batch row. scores -> w.
// ---------------------------------------------------------------------------
__global__ __launch_bounds__(256) void k_softmax(float* __restrict__ w) {
    const int b = blockIdx.x;
    const int tid = threadIdx.x;
    const int wid = tid >> 6, lane = tid & 63;
    float* row = w + (size_t)b * T;
    __shared__ float red[4];
    __shared__ float bmax_s, bsum_s;

    float lmax = -INFINITY;
    for (int t = tid; t < T; t += 256) lmax = fmaxf(lmax, row[t]);
#pragma unroll
    for (int off = 32; off >= 1; off >>= 1) lmax = fmaxf(lmax, __shfl_xor(lmax, off, 64));
    if (lane == 0) red[wid] = lmax;
    __syncthreads();
    if (tid == 0) bmax_s = fmaxf(fmaxf(red[0], red[1]), fmaxf(red[2], red[3]));
    __syncthreads();
    const float bmax = bmax_s;

    float lsum = 0.f;
    for (int t = tid; t < T; t += 256) lsum += __expf(row[t] - bmax);
#pragma unroll
    for (int off = 32; off >= 1; off >>= 1) lsum += __shfl_xor(lsum, off, 64);
    if (lane == 0) red[wid] = lsum;
    __syncthreads();
    if (tid == 0) bsum_s = red[0] + red[1] + red[2] + red[3];
    __syncthreads();
    const float inv = 1.f / bsum_s;

    for (int t = tid; t < T; t += 256) row[t] = __expf(row[t] - bmax) * inv;
}

// ---------------------------------------------------------------------------
// K4: ctx[b,e] = sum_t w[b,t]*h_enc[b,t,e].  Split T into chunks; partial
// accumulate in regs; f32 atomics into zero-initialized ctx.
// ---------------------------------------------------------------------------
#define TCH 256
__global__ __launch_bounds__(256) void k_ctx(const float* __restrict__ h_enc,
                                             const float* __restrict__ w,
                                             float* __restrict__ ctx) {
    const int b   = blockIdx.y;
    const int t0  = blockIdx.x * TCH;
    const int tid = threadIdx.x;  // covers e = 2*tid, 2*tid+1
    const float2* hb = (const float2*)(h_enc + ((size_t)b * T + t0) * DENC);
    const float* wrow = w + (size_t)b * T + t0;
    float ax = 0.f, ay = 0.f;
    for (int t = 0; t < TCH; ++t) {
        float wt = wrow[t];
        float2 hv = hb[(size_t)t * (DENC / 2) + tid];
        ax += wt * hv.x;
        ay += wt * hv.y;
    }
    atomicAdd(&ctx[b * DENC + 2 * tid + 0], ax);
    atomicAdd(&ctx[b * DENC + 2 * tid + 1], ay);
}

// ---------------------------------------------------------------------------
extern "C" void kernel_launch(void* const* d_in, const int* in_sizes, int n_in,
                              void* d_out, int out_size, void* d_ws, size_t ws_size,
                              hipStream_t stream) {
    const float* h_enc = (const float*)d_in[0];
    const float* h_dec = (const float*)d_in[1];
    const float* Wq_w  = (const float*)d_in[2];
    const float* Wq_b  = (const float*)d_in[3];
    const float* Wk_w  = (const float*)d_in[4];
    const float* Wk_b  = (const float*)d_in[5];
    const float* v_w   = (const float*)d_in[6];
    const int*   mask  = (const int*)d_in[7];

    float* out = (float*)d_out;
    float* ctx = out;               // [B, DENC]   = 32768 floats
    float* wts = out + B * DENC;    // [B, T]      = 262144 floats
    float* qq  = (float*)d_ws;      // [B, DATT]   = 64 KiB scratch

    // zero ctx region for K4's atomics (d_out is poisoned before each call)
    hipMemsetAsync(ctx, 0, (size_t)B * DENC * sizeof(float), stream);

    k_qproj<<<B, 256, 0, stream>>>(h_dec, Wq_w, Wq_b, Wk_b, qq);
    k_score<<<dim3(T / BM, B), 256, 0, stream>>>(h_enc, Wk_w, qq, v_w, mask, wts);
    k_softmax<<<B, 256, 0, stream>>>(wts);
    k_ctx<<<dim3(T / TCH, B), 256, 0, stream>>>(h_enc, wts, ctx);
}

// Round 2
// 837.411 us; speedup vs baseline: 2.0918x; 2.0918x over previous
//
#include <hip/hip_runtime.h>
#include <math.h>

#define B    64
#define T    4096
#define DENC 512
#define DDEC 512
#define DATT 256

typedef __attribute__((ext_vector_type(8))) short  short8;
typedef __attribute__((ext_vector_type(4))) float  f32x4;

// float -> bf16, round-to-nearest-even
__device__ __forceinline__ unsigned short f2bf(float f) {
    union { float f; unsigned u; } v; v.f = f;
    return (unsigned short)((v.u + 0x7fffu + ((v.u >> 16) & 1u)) >> 16);
}

// tanh via exp2 pipe: 1 - 2/(e^{2x}+1).  Saturates correctly at +-1.
__device__ __forceinline__ float tanh_fast(float x) {
    float e = __expf(2.0f * x);
    return 1.0f - 2.0f / (e + 1.0f);
}

// ---------------------------------------------------------------------------
// K0: Wk_w f32 [DATT][DENC] -> bf16 (RNE) in workspace, same layout.
// ---------------------------------------------------------------------------
__global__ __launch_bounds__(256) void k_wkconv(const float* __restrict__ Wk_w,
                                                unsigned short* __restrict__ WkB) {
    int i = (blockIdx.x * 256 + threadIdx.x) * 4;
    float4 v = *(const float4*)(Wk_w + i);
    ushort4 o;
    o.x = f2bf(v.x); o.y = f2bf(v.y); o.z = f2bf(v.z); o.w = f2bf(v.w);
    *(ushort4*)(WkB + i) = o;
}

// ---------------------------------------------------------------------------
// K1: qq[b,a] = dot(Wq_w[a,:], h_dec[b,:]) + Wq_b[a] + Wk_b[a]
// ---------------------------------------------------------------------------
__global__ __launch_bounds__(256) void k_qproj(const float* __restrict__ h_dec,
                                               const float* __restrict__ Wq_w,
                                               const float* __restrict__ Wq_b,
                                               const float* __restrict__ Wk_b,
                                               float* __restrict__ qq) {
    __shared__ float sh[DDEC];
    const int b = blockIdx.x;
    const int tid = threadIdx.x;
    ((float2*)sh)[tid] = ((const float2*)(h_dec + (size_t)b * DDEC))[tid];
    __syncthreads();
    const int a = tid;
    const float4* wr  = (const float4*)(Wq_w + (size_t)a * DDEC);
    const float4* shv = (const float4*)sh;
    float acc = 0.f;
#pragma unroll 4
    for (int i = 0; i < DDEC / 4; ++i) {
        float4 wv = wr[i];
        float4 hv = shv[i];
        acc += wv.x * hv.x + wv.y * hv.y + wv.z * hv.z + wv.w * hv.w;
    }
    qq[b * DATT + a] = acc + Wq_b[a] + Wk_b[a];
}

// ---------------------------------------------------------------------------
// K2: fused k-projection + additive score via bf16 MFMA.
//   Block tile: 128 t x 256 a, BK=32.  4 waves in 2x2 grid, each wave
//   64t x 128a = 4x8 tiles of mfma_f32_16x16x32_bf16.
//   LDS layout: row-major [rows][32 bf16], 16B chunks XOR-swizzled
//   (slot = kchunk ^ ((row>>1)&3)) -> conflict-free b128 frag reads.
//   B tile staged bf16 via global_load_lds(16B); A staged f32->bf16 cvt.
//   Epilogue: s[t] = sum_a v[a]*tanh(qq[a]+k[t,a]), shuffle+LDS reduce, mask.
// ---------------------------------------------------------------------------
#define BM 128
#define BK 32

__global__ __launch_bounds__(256, 2) void k_score(const float* __restrict__ h_enc,
                                                  const unsigned short* __restrict__ WkB,
                                                  const float* __restrict__ qq,
                                                  const float* __restrict__ v_w,
                                                  const int* __restrict__ mask,
                                                  float* __restrict__ scores) {
    __shared__ short As[BM * BK];    // 8 KB
    __shared__ short Bs[DATT * BK];  // 16 KB
    __shared__ float sp[2][BM];      // cross-wave a-partials

    const int tc   = blockIdx.x;
    const int b    = blockIdx.y;
    const int tid  = threadIdx.x;
    const int wv   = tid >> 6;
    const int lane = tid & 63;
    const int ln15 = lane & 15;
    const int qd   = lane >> 4;      // k-quad 0..3
    const int wv_t = wv >> 1;        // 0..1
    const int wv_a = wv & 1;         // 0..1
    const int t0   = tc * BM;

    f32x4 acc[4][8];
#pragma unroll
    for (int i = 0; i < 4; ++i)
#pragma unroll
        for (int j = 0; j < 8; ++j) acc[i][j] = (f32x4){0.f, 0.f, 0.f, 0.f};

    const float* Abase = h_enc + ((size_t)b * T + t0) * DENC;

    for (int k0 = 0; k0 < DENC; k0 += BK) {
        // ---- B tile: async bf16 global->LDS, 4 chunks of 16B per thread ----
#pragma unroll
        for (int it = 0; it < 4; ++it) {
            int idx = (wv * 4 + it) * 64 + lane;          // chunk 0..1023
            int r   = idx >> 2;                           // a-row
            int cc  = (idx & 3) ^ ((r >> 1) & 3);         // global k-chunk
            const unsigned short* gp = WkB + (size_t)r * DENC + k0 + cc * 8;
            short* lp = &Bs[(wv * 4 + it) * 64 * 8];      // wave-uniform base
            __builtin_amdgcn_global_load_lds(
                (const __attribute__((address_space(1))) unsigned int*)gp,
                (__attribute__((address_space(3))) unsigned int*)lp, 16, 0, 0);
        }
        // ---- A tile: f32 load, cvt to bf16, ds_write_b128, swizzled ----
#pragma unroll
        for (int it = 0; it < 2; ++it) {
            int idx = it * 256 + tid;                     // chunk 0..511
            int r   = idx >> 2;                           // t-row
            int cc  = (idx & 3) ^ ((r >> 1) & 3);
            const float* gp = Abase + (size_t)r * DENC + k0 + cc * 8;
            float4 v0 = *(const float4*)gp;
            float4 v1 = *(const float4*)(gp + 4);
            short8 pk;
            pk[0] = (short)f2bf(v0.x); pk[1] = (short)f2bf(v0.y);
            pk[2] = (short)f2bf(v0.z); pk[3] = (short)f2bf(v0.w);
            pk[4] = (short)f2bf(v1.x); pk[5] = (short)f2bf(v1.y);
            pk[6] = (short)f2bf(v1.z); pk[7] = (short)f2bf(v1.w);
            *(short8*)&As[idx * 8] = pk;
        }
        __syncthreads();

        // ---- fragments + MFMA ----
        short8 af[4], bfr[8];
#pragma unroll
        for (int ti = 0; ti < 4; ++ti) {
            int r = wv_t * 64 + ti * 16 + ln15;
            int s = qd ^ ((r >> 1) & 3);
            af[ti] = *(const short8*)&As[r * 32 + s * 8];
        }
#pragma unroll
        for (int tj = 0; tj < 8; ++tj) {
            int r = wv_a * 128 + tj * 16 + ln15;
            int s = qd ^ ((r >> 1) & 3);
            bfr[tj] = *(const short8*)&Bs[r * 32 + s * 8];
        }
#pragma unroll
        for (int ti = 0; ti < 4; ++ti)
#pragma unroll
            for (int tj = 0; tj < 8; ++tj)
                acc[ti][tj] = __builtin_amdgcn_mfma_f32_16x16x32_bf16(
                    af[ti], bfr[tj], acc[ti][tj], 0, 0, 0);
        __syncthreads();
    }

    // ---- epilogue: s[t] = sum_a v[a]*tanh(qq[a] + k[t,a]) ----
    float qr[8], vr[8];
#pragma unroll
    for (int tj = 0; tj < 8; ++tj) {
        int a = wv_a * 128 + tj * 16 + ln15;
        qr[tj] = qq[b * DATT + a];
        vr[tj] = v_w[a];
    }
#pragma unroll
    for (int ti = 0; ti < 4; ++ti) {
#pragma unroll
        for (int rg = 0; rg < 4; ++rg) {
            float s = 0.f;
#pragma unroll
            for (int tj = 0; tj < 8; ++tj)
                s += vr[tj] * tanh_fast(qr[tj] + acc[ti][tj][rg]);
            s += __shfl_xor(s, 1, 64);
            s += __shfl_xor(s, 2, 64);
            s += __shfl_xor(s, 4, 64);
            s += __shfl_xor(s, 8, 64);
            if (ln15 == 0)
                sp[wv_a][wv_t * 64 + ti * 16 + qd * 4 + rg] = s;
        }
    }
    __syncthreads();
    if (tid < BM) {
        int t = t0 + tid;
        float s = sp[0][tid] + sp[1][tid];
        bool m = mask[(size_t)b * T + t] != 0;
        scores[(size_t)b * T + t] = m ? s : -1e9f;
    }
}

// ---------------------------------------------------------------------------
// K3: in-place softmax over T per batch row.
// ---------------------------------------------------------------------------
__global__ __launch_bounds__(256) void k_softmax(float* __restrict__ w) {
    const int b = blockIdx.x;
    const int tid = threadIdx.x;
    const int wid = tid >> 6, lane = tid & 63;
    float* row = w + (size_t)b * T;
    __shared__ float red[4];
    __shared__ float bmax_s, bsum_s;

    float x[T / 256];
#pragma unroll
    for (int i = 0; i < T / 256; ++i) x[i] = row[tid + i * 256];

    float lmax = -INFINITY;
#pragma unroll
    for (int i = 0; i < T / 256; ++i) lmax = fmaxf(lmax, x[i]);
#pragma unroll
    for (int off = 32; off >= 1; off >>= 1) lmax = fmaxf(lmax, __shfl_xor(lmax, off, 64));
    if (lane == 0) red[wid] = lmax;
    __syncthreads();
    if (tid == 0) bmax_s = fmaxf(fmaxf(red[0], red[1]), fmaxf(red[2], red[3]));
    __syncthreads();
    const float bmax = bmax_s;

    float lsum = 0.f;
#pragma unroll
    for (int i = 0; i < T / 256; ++i) { x[i] = __expf(x[i] - bmax); lsum += x[i]; }
#pragma unroll
    for (int off = 32; off >= 1; off >>= 1) lsum += __shfl_xor(lsum, off, 64);
    if (lane == 0) red[wid] = lsum;
    __syncthreads();
    if (tid == 0) bsum_s = red[0] + red[1] + red[2] + red[3];
    __syncthreads();
    const float inv = 1.f / bsum_s;
#pragma unroll
    for (int i = 0; i < T / 256; ++i) row[tid + i * 256] = x[i] * inv;
}

// ---------------------------------------------------------------------------
// K4: ctx[b,e] = sum_t w[b,t]*h_enc[b,t,e].  float4 lanes, w staged in LDS,
// 2-way t-parallel, LDS combine, 4 atomics/thread into zeroed ctx.
// ---------------------------------------------------------------------------
#define TCH 256
__global__ __launch_bounds__(256) void k_ctx(const float* __restrict__ h_enc,
                                             const float* __restrict__ w,
                                             float* __restrict__ ctx) {
    const int b   = blockIdx.y;
    const int t0  = blockIdx.x * TCH;
    const int tid = threadIdx.x;
    __shared__ float ws[TCH];
    __shared__ float red[128][4];
    ws[tid] = w[(size_t)b * T + t0 + tid];
    __syncthreads();
    const int e4 = tid & 127, tp = tid >> 7;
    const float4* hb = (const float4*)(h_enc + ((size_t)b * T + t0) * DENC);
    float ax = 0.f, ay = 0.f, az = 0.f, aw = 0.f;
#pragma unroll 4
    for (int t = tp; t < TCH; t += 2) {
        float wt = ws[t];
        float4 hv = hb[(size_t)t * 128 + e4];
        ax = fmaf(wt, hv.x, ax);
        ay = fmaf(wt, hv.y, ay);
        az = fmaf(wt, hv.z, az);
        aw = fmaf(wt, hv.w, aw);
    }
    if (tp) { red[e4][0] = ax; red[e4][1] = ay; red[e4][2] = az; red[e4][3] = aw; }
    __syncthreads();
    if (!tp) {
        ax += red[e4][0]; ay += red[e4][1]; az += red[e4][2]; aw += red[e4][3];
        float* c = ctx + b * DENC + e4 * 4;
        atomicAdd(c + 0, ax);
        atomicAdd(c + 1, ay);
        atomicAdd(c + 2, az);
        atomicAdd(c + 3, aw);
    }
}

// ---------------------------------------------------------------------------
extern "C" void kernel_launch(void* const* d_in, const int* in_sizes, int n_in,
                              void* d_out, int out_size, void* d_ws, size_t ws_size,
                              hipStream_t stream) {
    const float* h_enc = (const float*)d_in[0];
    const float* h_dec = (const float*)d_in[1];
    const float* Wq_w  = (const float*)d_in[2];
    const float* Wq_b  = (const float*)d_in[3];
    const float* Wk_w  = (const float*)d_in[4];
    const float* Wk_b  = (const float*)d_in[5];
    const float* v_w   = (const float*)d_in[6];
    const int*   mask  = (const int*)d_in[7];

    float* out = (float*)d_out;
    float* ctx = out;               // [B, DENC]
    float* wts = out + B * DENC;    // [B, T]
    float*          qq  = (float*)d_ws;                                   // 64 KB
    unsigned short* WkB = (unsigned short*)((char*)d_ws + B * DATT * 4);  // 256 KB

    hipMemsetAsync(ctx, 0, (size_t)B * DENC * sizeof(float), stream);

    k_wkconv<<<DATT * DENC / 4 / 256, 256, 0, stream>>>(Wk_w, WkB);
    k_qproj<<<B, 256, 0, stream>>>(h_dec, Wq_w, Wq_b, Wk_b, qq);
    k_score<<<dim3(T / BM, B), 256, 0, stream>>>(h_enc, WkB, qq, v_w, mask, wts);
    k_softmax<<<B, 256, 0, stream>>>(wts);
    k_ctx<<<dim3(T / TCH, B), 256, 0, stream>>>(h_enc, wts, ctx);
}